// Round 7
// baseline (177.384 us; speedup 1.0000x reference)
//
#include <hip/hip_runtime.h>
#include <hip/hip_bf16.h>

// Problem constants (fixed by the reference)
#define NN 100000      // nodes
#define FF 128         // in features
#define DEG 16
#define OUTC 128       // out features
#define NSTRIPS 6250   // NN/16, exact

typedef __attribute__((ext_vector_type(8))) short short8;    // 8 bf16 in 4 VGPRs
typedef __attribute__((ext_vector_type(4))) float float4v;   // MFMA acc
typedef __attribute__((ext_vector_type(2))) float float2v;

__device__ __forceinline__ unsigned short f2b(float f) {
    union { float f; unsigned u; } v; v.f = f;
    unsigned r = v.u + 0x7fff + ((v.u >> 16) & 1);   // RNE
    return (unsigned short)(r >> 16);
}
__device__ __forceinline__ float b2f(unsigned bits16) {
    union { unsigned u; float f; } v; v.u = bits16 << 16; return v.f;
}

// ---- Kernel A: fused prep.
//      Blocks [0,12500): x -> bf16 table + CHUNKED fp8 table.
//        xf8c[c][node][8 dwords]: chunk c = features [32c,32c+32) (3.2 MB/chunk,
//        fits one 4 MiB per-XCD L2 — consumed chunk-per-XCD by gather_x).
//      Blocks [12500,12628): pack W into MFMA B-frag layout (bf16). ----
__global__ __launch_bounds__(256) void prep_xw(const float4* __restrict__ x,
                                               uint2* __restrict__ xb,
                                               unsigned* __restrict__ xf8c,
                                               const float* __restrict__ w,
                                               unsigned short* __restrict__ wp,
                                               int use_f8) {
    int b = blockIdx.x;
    if (b < 12500) {
        int t = b * 256 + threadIdx.x;           // < 3,200,000
        float4 v = x[t];
        uint2 o;
        o.x = (unsigned)f2b(v.x) | ((unsigned)f2b(v.y) << 16);
        o.y = (unsigned)f2b(v.z) | ((unsigned)f2b(v.w) << 16);
        xb[t] = o;
        if (use_f8) {
            int u = __builtin_amdgcn_cvt_pk_fp8_f32(v.x, v.y, 0, false);   // bytes 0,1
            u = __builtin_amdgcn_cvt_pk_fp8_f32(v.z, v.w, u, true);        // bytes 2,3
            int n = t >> 5, wd = t & 31;         // node, global dword (feature/4)
            // chunk = wd>>3, within-chunk dword = wd&7  [R2-proven mapping]
            xf8c[(size_t)(wd >> 3) * (NN * 8) + (size_t)n * 8 + (wd & 7)] = (unsigned)u;
        }
    } else {
        // wpack[((ct*8+kk)*64+lane)*8+j] = W[kk*32+(lane>>4)*8+j][ct*16+(lane&15)]
        int t = (b - 12500) * 256 + threadIdx.x; // < 32768
        int j = t & 7, lane = (t >> 3) & 63, kk = (t >> 9) & 7, ct = t >> 12;
        int k = kk * 32 + (lane >> 4) * 8 + j;
        int c = ct * 16 + (lane & 15);
        wp[t] = f2b(w[k * 128 + c]);
    }
}

// ---- Kernel C: gather-mean, chunk-per-XCD L2-resident fp8 reads.
//  R6 falsified the issue-rate model (removing 14/34 vmem insts was neutral)
//  -> gather is miss-LATENCY bound (12.8 MB table >> 4 MiB per-XCD L2).
//  Fix: chunk c = (blockIdx&7)>>1, so each XCD pair touches only its 3.2 MB
//  chunk for the whole kernel -> row reads become L2 hits. Same instruction
//  structure: 16 uint4 row loads per wave (1 per k), 32 nodes x 2 half-rows
//  per wave. k-order 0..15 per feature unchanged -> bit-identical hb. ----
#define GATHER_BLOCKS 3128             // 391*8; nb = (bid>>3)*2+(bid&1) in [0,782)
__global__ __launch_bounds__(256) void gather_x(const unsigned* __restrict__ xf8c,
                                                const int* __restrict__ adj,
                                                uint4* __restrict__ hb) {
    const int bid = blockIdx.x;
    const int c = (bid & 7) >> 1;                // chunk, pinned per XCD pair
    const int nb = ((bid >> 3) << 1) | (bid & 1);  // node-block 0..781
    const int lane = threadIdx.x & 63;
    const int wv = threadIdx.x >> 6;             // 0..3
    const int g = nb * 128 + wv * 32 + (lane >> 1);  // node (128 per block)
    const int half = lane & 1;                   // which 16B of the 32B chunk row
    if (g >= NN) return;

    const uint4* rows = (const uint4*)xf8c + (size_t)c * (NN * 2) + half;

    float a[16];
#pragma unroll
    for (int i = 0; i < 16; ++i) a[i] = 0.f;

#pragma unroll
    for (int k = 0; k < DEG; ++k) {
        int s = adj[2 * (g + k * NN) + 1];       // lane-pair broadcast
        uint4 v = rows[(size_t)s * 2];           // 16B of the 32B chunk row (L2-hit)
#pragma unroll
        for (int d = 0; d < 4; ++d) {
            unsigned wd = (&v.x)[d];
            float2v lo = __builtin_amdgcn_cvt_pk_f32_fp8(wd, false);
            float2v hi = __builtin_amdgcn_cvt_pk_f32_fp8(wd, true);
            a[4 * d + 0] += lo[0]; a[4 * d + 1] += lo[1];
            a[4 * d + 2] += hi[0]; a[4 * d + 3] += hi[1];
        }
    }
    unsigned ow[8];
#pragma unroll
    for (int d = 0; d < 8; ++d)
        ow[d] = (unsigned)f2b(a[2 * d] * 0.0625f)
              | ((unsigned)f2b(a[2 * d + 1] * 0.0625f) << 16);
    // lane covers features c*32 + half*16 + [0,16) of node g:
    // hb uint4 index = g*16 + c*4 + half*2 (and +1)
    uint4 o0; o0.x = ow[0]; o0.y = ow[1]; o0.z = ow[2]; o0.w = ow[3];
    uint4 o1; o1.x = ow[4]; o1.y = ow[5]; o1.z = ow[6]; o1.w = ow[7];
    size_t bi = (size_t)g * 16 + c * 4 + half * 2;
    hb[bi]     = o0;
    hb[bi + 1] = o1;
}

// ---- Kernel C (bf16 fallback if workspace too small): round-1 version ----
__global__ __launch_bounds__(256) void gather_k(const unsigned* __restrict__ xb,
                                                const int* __restrict__ adj,
                                                unsigned* __restrict__ hb) {
    int node = (int)((blockIdx.x * 256 + threadIdx.x) >> 6);
    int lane = threadIdx.x & 63;
    if (node >= NN) return;
    float a0 = 0.f, a1 = 0.f;
#pragma unroll
    for (int k = 0; k < DEG; ++k) {
        int s = adj[2 * (node + k * NN) + 1];
        unsigned v = xb[(size_t)s * 64 + lane];
        a0 += b2f(v & 0xffffu);
        a1 += b2f(v >> 16);
    }
    a0 *= (1.f / 16.f); a1 *= (1.f / 16.f);
    hb[(size_t)node * 64 + lane] = (unsigned)f2b(a0) | ((unsigned)f2b(a1) << 16);
}

// ---- Kernel D: out = sigmoid([x|h] @ W + b) — proven version, untouched.
//      1024 blocks: 3 strips/wave amortizes the 32KB/wave B-frag prologue;
//      2048 blocks measured WORSE (doubled B-prologue L2 traffic). ----
#define GEMM_BLOCKS 1024
#define WAVES_PER_HALF 2048            // GEMM_BLOCKS*4/2
__global__ __launch_bounds__(256, 2) void gemm_k(const unsigned short* __restrict__ xb,
                                                 const unsigned short* __restrict__ hb,
                                                 const unsigned short* __restrict__ wp,
                                                 const float* __restrict__ bias,
                                                 float* __restrict__ out) {
    const int wv = blockIdx.x * 4 + (threadIdx.x >> 6);
    const int lane = threadIdx.x & 63;
    const int half = wv & 1;           // which 64-col half
    const int wslot = wv >> 1;

    short8 bfrag[4][8];
    const short8* wpv = (const short8*)wp;
#pragma unroll
    for (int j = 0; j < 4; ++j) {
        int ct = half * 4 + j;
#pragma unroll
        for (int kk = 0; kk < 8; ++kk)
            bfrag[j][kk] = wpv[(ct * 8 + kk) * 64 + lane];
    }
    float bval[4];
#pragma unroll
    for (int j = 0; j < 4; ++j)
        bval[j] = bias[(half * 4 + j) * 16 + (lane & 15)];

    const int arow = lane & 15;
    const int kg = lane >> 4;

    for (int s = wslot; s < NSTRIPS; s += WAVES_PER_HALF) {
        int node = s * 16 + arow;
        const short8* xrow = (const short8*)(xb + (size_t)node * 128) + kg;
        const short8* hrow = (const short8*)(hb + (size_t)node * 128) + kg;

        float4v acc[4];
#pragma unroll
        for (int j = 0; j < 4; ++j) acc[j] = (float4v){0.f, 0.f, 0.f, 0.f};

#pragma unroll
        for (int kk = 0; kk < 8; ++kk) {
            short8 afrag = (kk < 4) ? xrow[kk * 4] : hrow[(kk - 4) * 4];
#pragma unroll
            for (int j = 0; j < 4; ++j)
                acc[j] = __builtin_amdgcn_mfma_f32_16x16x32_bf16(afrag, bfrag[j][kk], acc[j], 0, 0, 0);
        }
        // Epilogue: D col = lane&15, row = (lane>>4)*4 + r  [verified mapping]
#pragma unroll
        for (int j = 0; j < 4; ++j) {
            int col = (half * 4 + j) * 16 + (lane & 15);
#pragma unroll
            for (int r = 0; r < 4; ++r) {
                float v = acc[j][r] + bval[j];
                v = 1.f / (1.f + __expf(-v));
                out[(size_t)(s * 16 + kg * 4 + r) * 128 + col] = v;
            }
        }
    }
}

extern "C" void kernel_launch(void* const* d_in, const int* in_sizes, int n_in,
                              void* d_out, int out_size, void* d_ws, size_t ws_size,
                              hipStream_t stream) {
    const float* x    = (const float*)d_in[0];   // [N,128]
    const int*   adj  = (const int*)d_in[1];     // [E,2] (dst,src) int32
    const float* w    = (const float*)d_in[3];   // [256,128]
    const float* bias = (const float*)d_in[4];   // [128]
    float* out = (float*)d_out;

    // Workspace layout:
    //   xb:   N*128 bf16 = 25,600,000 B @ 0
    //   hb:   N*128 bf16 = 25,600,000 B @ 25,600,000
    //   wp:   32768 bf16 =     65,536 B @ 51,200,000
    //   xf8c: N*128 fp8  = 12,800,000 B @ 51,265,536   (total 64,065,536)
    unsigned short* xb = (unsigned short*)d_ws;
    unsigned short* hb = (unsigned short*)((char*)d_ws + 25600000);
    unsigned short* wp = (unsigned short*)((char*)d_ws + 51200000);
    unsigned* xf8c = (unsigned*)((char*)d_ws + 51265536);

    const bool use_f8 = ws_size >= 64065536;   // ws_size constant across calls

    prep_xw<<<12628, 256, 0, stream>>>((const float4*)x, (uint2*)xb, xf8c, w, wp,
                                       use_f8 ? 1 : 0);
    if (use_f8)
        gather_x<<<GATHER_BLOCKS, 256, 0, stream>>>(xf8c, adj, (uint4*)hb);
    else
        gather_k<<<25000, 256, 0, stream>>>((const unsigned*)xb, adj, (unsigned*)hb);
    gemm_k<<<GEMM_BLOCKS, 256, 0, stream>>>(xb, hb, wp, bias, out);
}

// Round 8
// 176.780 us; speedup vs baseline: 1.0034x; 1.0034x over previous
//
#include <hip/hip_runtime.h>
#include <hip/hip_bf16.h>

// Problem constants (fixed by the reference)
#define NN 100000      // nodes
#define FF 128         // in features
#define DEG 16
#define OUTC 128       // out features
#define NSTRIPS 6250   // NN/16, exact

typedef __attribute__((ext_vector_type(8))) short short8;    // 8 bf16 in 4 VGPRs
typedef __attribute__((ext_vector_type(4))) float float4v;   // MFMA acc
typedef __attribute__((ext_vector_type(2))) float float2v;
typedef __attribute__((ext_vector_type(4))) unsigned uint4v; // for nt ld/st
typedef __attribute__((ext_vector_type(2))) unsigned uint2v;
typedef __attribute__((ext_vector_type(4))) float floatv4;

__device__ __forceinline__ unsigned short f2b(float f) {
    union { float f; unsigned u; } v; v.f = f;
    unsigned r = v.u + 0x7fff + ((v.u >> 16) & 1);   // RNE
    return (unsigned short)(r >> 16);
}
__device__ __forceinline__ float b2f(unsigned bits16) {
    union { unsigned u; float f; } v; v.u = bits16 << 16; return v.f;
}

// ---- Kernel A: fused prep (R3-proven structure; nt hints on pure streams).
//      Blocks [0,12500): x -> bf16 + fp8 tables.
//      Blocks [12500,12628): pack W into MFMA B-frag layout (bf16). ----
__global__ __launch_bounds__(256) void prep_xw(const floatv4* __restrict__ x,
                                               uint2v* __restrict__ xb,
                                               unsigned* __restrict__ xf8,
                                               const float* __restrict__ w,
                                               unsigned short* __restrict__ wp) {
    int b = blockIdx.x;
    if (b < 12500) {
        int t = b * 256 + threadIdx.x;           // < 3,200,000
        floatv4 v = __builtin_nontemporal_load(&x[t]);   // read-once stream
        uint2v o;
        o.x = (unsigned)f2b(v.x) | ((unsigned)f2b(v.y) << 16);
        o.y = (unsigned)f2b(v.z) | ((unsigned)f2b(v.w) << 16);
        __builtin_nontemporal_store(o, &xb[t]);          // write-once, read much later
        int u = __builtin_amdgcn_cvt_pk_fp8_f32(v.x, v.y, 0, false);   // bytes 0,1
        u = __builtin_amdgcn_cvt_pk_fp8_f32(v.z, v.w, u, true);        // bytes 2,3
        xf8[t] = (unsigned)u;                    // read soon by gather: keep cached
    } else {
        // wpack[((ct*8+kk)*64+lane)*8+j] = W[kk*32+(lane>>4)*8+j][ct*16+(lane&15)]
        int t = (b - 12500) * 256 + threadIdx.x; // < 32768
        int j = t & 7, lane = (t >> 3) & 63, kk = (t >> 9) & 7, ct = t >> 12;
        int k = kk * 32 + (lane >> 4) * 8 + j;
        int c = ct * 16 + (lane & 15);
        wp[t] = f2b(w[k * 128 + c]);
    }
}

// ---- Kernel C (wide fp8): gather-mean with 16B-per-lane loads (R3-proven).
//  One wave per 8 nodes: lane = (node n = lane>>3, uint4-chunk j = lane&7);
//  each fp8 row = 128B = exactly one cache line, 8 lanes per row.
//  nt hints: adj is a read-once stream, hb a write-once stream — keep both
//  out of L2 so the 12.8MB table holds as much of the 4MiB/XCD L2 as possible.
//  Row loads stay cached. k-order 0..15 unchanged -> bit-identical hb. ----
__global__ __launch_bounds__(256) void gather_w(const uint4v* __restrict__ xf8v,
                                                const int* __restrict__ adj,
                                                uint4v* __restrict__ hb) {
    const int wv = (blockIdx.x * 256 + threadIdx.x) >> 6;  // 0..12499
    const int lane = threadIdx.x & 63;
    const int n = lane >> 3;          // node within octet
    const int j = lane & 7;           // uint4 (16 features) within 128B row
    const int g = wv * 8 + n;         // global node

    float a[16];
#pragma unroll
    for (int i = 0; i < 16; ++i) a[i] = 0.f;

#pragma unroll
    for (int k = 0; k < DEG; ++k) {
        int s = __builtin_nontemporal_load(&adj[2 * (g + k * NN) + 1]);
        uint4v v = xf8v[(size_t)s * 8 + j];       // 16B of the 128B fp8 row (cached)
#pragma unroll
        for (int d = 0; d < 4; ++d) {
            unsigned wd = v[d];
            float2v lo = __builtin_amdgcn_cvt_pk_f32_fp8(wd, false);
            float2v hi = __builtin_amdgcn_cvt_pk_f32_fp8(wd, true);
            a[4 * d + 0] += lo[0]; a[4 * d + 1] += lo[1];
            a[4 * d + 2] += hi[0]; a[4 * d + 3] += hi[1];
        }
    }
    unsigned ow[8];
#pragma unroll
    for (int d = 0; d < 8; ++d)
        ow[d] = (unsigned)f2b(a[2 * d] * 0.0625f)
              | ((unsigned)f2b(a[2 * d + 1] * 0.0625f) << 16);
    // bf16 row = 256B = 16 uint4; lane j owns uint4 slots 2j, 2j+1.
    uint4v o0; o0.x = ow[0]; o0.y = ow[1]; o0.z = ow[2]; o0.w = ow[3];
    uint4v o1; o1.x = ow[4]; o1.y = ow[5]; o1.z = ow[6]; o1.w = ow[7];
    __builtin_nontemporal_store(o0, &hb[(size_t)g * 16 + 2 * j]);
    __builtin_nontemporal_store(o1, &hb[(size_t)g * 16 + 2 * j + 1]);
}

// ---- Kernel C (bf16 fallback if workspace too small): round-1 version ----
__global__ __launch_bounds__(256) void gather_k(const unsigned* __restrict__ xb,
                                                const int* __restrict__ adj,
                                                unsigned* __restrict__ hb) {
    int node = (int)((blockIdx.x * 256 + threadIdx.x) >> 6);
    int lane = threadIdx.x & 63;
    if (node >= NN) return;
    float a0 = 0.f, a1 = 0.f;
#pragma unroll
    for (int k = 0; k < DEG; ++k) {
        int s = adj[2 * (node + k * NN) + 1];
        unsigned v = xb[(size_t)s * 64 + lane];
        a0 += b2f(v & 0xffffu);
        a1 += b2f(v >> 16);
    }
    a0 *= (1.f / 16.f); a1 *= (1.f / 16.f);
    hb[(size_t)node * 64 + lane] = (unsigned)f2b(a0) | ((unsigned)f2b(a1) << 16);
}

// ---- Kernel D: out = sigmoid([x|h] @ W + b) — proven version; nt out stores.
//      1024 blocks: 3 strips/wave amortizes the 32KB/wave B-frag prologue;
//      2048 blocks measured WORSE (doubled B-prologue L2 traffic). ----
#define GEMM_BLOCKS 1024
#define WAVES_PER_HALF 2048            // GEMM_BLOCKS*4/2
__global__ __launch_bounds__(256, 2) void gemm_k(const unsigned short* __restrict__ xb,
                                                 const unsigned short* __restrict__ hb,
                                                 const unsigned short* __restrict__ wp,
                                                 const float* __restrict__ bias,
                                                 float* __restrict__ out) {
    const int wv = blockIdx.x * 4 + (threadIdx.x >> 6);
    const int lane = threadIdx.x & 63;
    const int half = wv & 1;           // which 64-col half
    const int wslot = wv >> 1;

    short8 bfrag[4][8];
    const short8* wpv = (const short8*)wp;
#pragma unroll
    for (int j = 0; j < 4; ++j) {
        int ct = half * 4 + j;
#pragma unroll
        for (int kk = 0; kk < 8; ++kk)
            bfrag[j][kk] = wpv[(ct * 8 + kk) * 64 + lane];
    }
    float bval[4];
#pragma unroll
    for (int j = 0; j < 4; ++j)
        bval[j] = bias[(half * 4 + j) * 16 + (lane & 15)];

    const int arow = lane & 15;
    const int kg = lane >> 4;

    for (int s = wslot; s < NSTRIPS; s += WAVES_PER_HALF) {
        int node = s * 16 + arow;
        const short8* xrow = (const short8*)(xb + (size_t)node * 128) + kg;
        const short8* hrow = (const short8*)(hb + (size_t)node * 128) + kg;

        float4v acc[4];
#pragma unroll
        for (int j = 0; j < 4; ++j) acc[j] = (float4v){0.f, 0.f, 0.f, 0.f};

#pragma unroll
        for (int kk = 0; kk < 8; ++kk) {
            short8 afrag = (kk < 4) ? xrow[kk * 4] : hrow[(kk - 4) * 4];
#pragma unroll
            for (int j = 0; j < 4; ++j)
                acc[j] = __builtin_amdgcn_mfma_f32_16x16x32_bf16(afrag, bfrag[j][kk], acc[j], 0, 0, 0);
        }
        // Epilogue: D col = lane&15, row = (lane>>4)*4 + r  [verified mapping]
#pragma unroll
        for (int j = 0; j < 4; ++j) {
            int col = (half * 4 + j) * 16 + (lane & 15);
#pragma unroll
            for (int r = 0; r < 4; ++r) {
                float v = acc[j][r] + bval[j];
                v = 1.f / (1.f + __expf(-v));
                __builtin_nontemporal_store(
                    v, &out[(size_t)(s * 16 + kg * 4 + r) * 128 + col]);
            }
        }
    }
}

extern "C" void kernel_launch(void* const* d_in, const int* in_sizes, int n_in,
                              void* d_out, int out_size, void* d_ws, size_t ws_size,
                              hipStream_t stream) {
    const float* x    = (const float*)d_in[0];   // [N,128]
    const int*   adj  = (const int*)d_in[1];     // [E,2] (dst,src) int32
    const float* w    = (const float*)d_in[3];   // [256,128]
    const float* bias = (const float*)d_in[4];   // [128]
    float* out = (float*)d_out;

    // Workspace layout (round-0 proven):
    //   xb:  N*128 bf16 = 25,600,000 B @ 0
    //   hb:  N*128 bf16 = 25,600,000 B @ 25,600,000
    //   wp:  32768 bf16 =     65,536 B @ 51,200,000
    //   xf8: N*128 fp8  = 12,800,000 B @ 51,265,536   (total 64,065,536)
    unsigned short* xb = (unsigned short*)d_ws;
    unsigned short* hb = (unsigned short*)((char*)d_ws + 25600000);
    unsigned short* wp = (unsigned short*)((char*)d_ws + 51200000);
    unsigned* xf8 = (unsigned*)((char*)d_ws + 51265536);

    const bool use_f8 = ws_size >= 64065536;   // ws_size constant across calls

    prep_xw<<<12628, 256, 0, stream>>>((const floatv4*)x, (uint2v*)xb, xf8, w, wp);
    if (use_f8)
        gather_w<<<3125, 256, 0, stream>>>((const uint4v*)xf8, adj, (uint4v*)hb);
    else
        gather_k<<<25000, 256, 0, stream>>>((const unsigned*)xb, adj, (unsigned*)hb);
    gemm_k<<<GEMM_BLOCKS, 256, 0, stream>>>(xb, hb, wp, bias, out);
}

// Round 9
// 162.485 us; speedup vs baseline: 1.0917x; 1.0880x over previous
//
#include <hip/hip_runtime.h>
#include <hip/hip_bf16.h>

// Problem constants (fixed by the reference)
#define NN 100000      // nodes
#define FF 128         // in features
#define DEG 16
#define OUTC 128       // out features
#define NSTRIPS 6250   // NN/16, exact

typedef __attribute__((ext_vector_type(8))) short short8;    // 8 bf16 in 4 VGPRs
typedef __attribute__((ext_vector_type(4))) float float4v;   // MFMA acc
typedef __attribute__((ext_vector_type(2))) float float2v;

__device__ __forceinline__ unsigned short f2b(float f) {
    union { float f; unsigned u; } v; v.f = f;
    unsigned r = v.u + 0x7fff + ((v.u >> 16) & 1);   // RNE
    return (unsigned short)(r >> 16);
}
__device__ __forceinline__ float b2f(unsigned bits16) {
    union { unsigned u; float f; } v; v.u = bits16 << 16; return v.f;
}

// ---- Kernel A: fused prep (PROVEN 161.4us config — do not touch).
//      Blocks [0,12500): x -> bf16 + fp8 tables.
//      Blocks [12500,12628): pack W into MFMA B-frag layout (bf16).
//  NOTE (R8): nontemporal hints on these streams REGRESS by ~14us
//  (nt stores break L2 write-combining). Keep plain loads/stores. ----
__global__ __launch_bounds__(256) void prep_xw(const float4* __restrict__ x,
                                               uint2* __restrict__ xb,
                                               unsigned* __restrict__ xf8,
                                               const float* __restrict__ w,
                                               unsigned short* __restrict__ wp) {
    int b = blockIdx.x;
    if (b < 12500) {
        int t = b * 256 + threadIdx.x;           // < 3,200,000
        float4 v = x[t];
        uint2 o;
        o.x = (unsigned)f2b(v.x) | ((unsigned)f2b(v.y) << 16);
        o.y = (unsigned)f2b(v.z) | ((unsigned)f2b(v.w) << 16);
        xb[t] = o;
        int u = __builtin_amdgcn_cvt_pk_fp8_f32(v.x, v.y, 0, false);   // bytes 0,1
        u = __builtin_amdgcn_cvt_pk_fp8_f32(v.z, v.w, u, true);        // bytes 2,3
        xf8[t] = (unsigned)u;
    } else {
        // wpack[((ct*8+kk)*64+lane)*8+j] = W[kk*32+(lane>>4)*8+j][ct*16+(lane&15)]
        int t = (b - 12500) * 256 + threadIdx.x; // < 32768
        int j = t & 7, lane = (t >> 3) & 63, kk = (t >> 9) & 7, ct = t >> 12;
        int k = kk * 32 + (lane >> 4) * 8 + j;
        int c = ct * 16 + (lane & 15);
        wp[t] = f2b(w[k * 128 + c]);
    }
}

// ---- Kernel C (wide fp8): gather-mean with 16B-per-lane loads.
//  R3-proven: one wave per 8 nodes, lane = (node n = lane>>3, chunk j = lane&7),
//  each fp8 row = 128B = one cache line served to 8 lanes.
//  Measured findings across R4-R8: NOT vmem-issue-bound (R6 LDS adj staging
//  neutral), NOT fixable by L2 chunking (R2 neutral, R7 regression), nt hints
//  regress (R8). This is the service-latency floor for a 12.8MB-footprint
//  random 128B-row read (204.8MB logical). k-order 0..15 -> proven absmax. ----
__global__ __launch_bounds__(256) void gather_w(const uint4* __restrict__ xf8v,
                                                const int* __restrict__ adj,
                                                uint4* __restrict__ hb) {
    const int wv = (blockIdx.x * 256 + threadIdx.x) >> 6;  // 0..12499
    const int lane = threadIdx.x & 63;
    const int n = lane >> 3;          // node within octet
    const int j = lane & 7;           // uint4 (16 features) within 128B row
    const int g = wv * 8 + n;         // global node

    float a[16];
#pragma unroll
    for (int i = 0; i < 16; ++i) a[i] = 0.f;

#pragma unroll
    for (int k = 0; k < DEG; ++k) {
        int s = adj[2 * (g + k * NN) + 1];        // 8-lane broadcast, 1 line/wave
        uint4 v = xf8v[(size_t)s * 8 + j];        // 16B of the 128B fp8 row
#pragma unroll
        for (int d = 0; d < 4; ++d) {
            unsigned wd = (&v.x)[d];
            float2v lo = __builtin_amdgcn_cvt_pk_f32_fp8(wd, false);
            float2v hi = __builtin_amdgcn_cvt_pk_f32_fp8(wd, true);
            a[4 * d + 0] += lo[0]; a[4 * d + 1] += lo[1];
            a[4 * d + 2] += hi[0]; a[4 * d + 3] += hi[1];
        }
    }
    unsigned ow[8];
#pragma unroll
    for (int d = 0; d < 8; ++d)
        ow[d] = (unsigned)f2b(a[2 * d] * 0.0625f)
              | ((unsigned)f2b(a[2 * d + 1] * 0.0625f) << 16);
    // bf16 row = 256B = 16 uint4; lane j owns uint4 slots 2j, 2j+1.
    uint4 o0; o0.x = ow[0]; o0.y = ow[1]; o0.z = ow[2]; o0.w = ow[3];
    uint4 o1; o1.x = ow[4]; o1.y = ow[5]; o1.z = ow[6]; o1.w = ow[7];
    hb[(size_t)g * 16 + 2 * j]     = o0;
    hb[(size_t)g * 16 + 2 * j + 1] = o1;
}

// ---- Kernel C (bf16 fallback if workspace too small): round-1 version ----
__global__ __launch_bounds__(256) void gather_k(const unsigned* __restrict__ xb,
                                                const int* __restrict__ adj,
                                                unsigned* __restrict__ hb) {
    int node = (int)((blockIdx.x * 256 + threadIdx.x) >> 6);
    int lane = threadIdx.x & 63;
    if (node >= NN) return;
    float a0 = 0.f, a1 = 0.f;
#pragma unroll
    for (int k = 0; k < DEG; ++k) {
        int s = adj[2 * (node + k * NN) + 1];
        unsigned v = xb[(size_t)s * 64 + lane];
        a0 += b2f(v & 0xffffu);
        a1 += b2f(v >> 16);
    }
    a0 *= (1.f / 16.f); a1 *= (1.f / 16.f);
    hb[(size_t)node * 64 + lane] = (unsigned)f2b(a0) | ((unsigned)f2b(a1) << 16);
}

// ---- Kernel D: out = sigmoid([x|h] @ W + b) — proven version, untouched.
//      1024 blocks: 3 strips/wave amortizes the 32KB/wave B-frag prologue;
//      2048 blocks measured WORSE (doubled B-prologue L2 traffic). ----
#define GEMM_BLOCKS 1024
#define WAVES_PER_HALF 2048            // GEMM_BLOCKS*4/2
__global__ __launch_bounds__(256, 2) void gemm_k(const unsigned short* __restrict__ xb,
                                                 const unsigned short* __restrict__ hb,
                                                 const unsigned short* __restrict__ wp,
                                                 const float* __restrict__ bias,
                                                 float* __restrict__ out) {
    const int wv = blockIdx.x * 4 + (threadIdx.x >> 6);
    const int lane = threadIdx.x & 63;
    const int half = wv & 1;           // which 64-col half
    const int wslot = wv >> 1;

    short8 bfrag[4][8];
    const short8* wpv = (const short8*)wp;
#pragma unroll
    for (int j = 0; j < 4; ++j) {
        int ct = half * 4 + j;
#pragma unroll
        for (int kk = 0; kk < 8; ++kk)
            bfrag[j][kk] = wpv[(ct * 8 + kk) * 64 + lane];
    }
    float bval[4];
#pragma unroll
    for (int j = 0; j < 4; ++j)
        bval[j] = bias[(half * 4 + j) * 16 + (lane & 15)];

    const int arow = lane & 15;
    const int kg = lane >> 4;

    for (int s = wslot; s < NSTRIPS; s += WAVES_PER_HALF) {
        int node = s * 16 + arow;
        const short8* xrow = (const short8*)(xb + (size_t)node * 128) + kg;
        const short8* hrow = (const short8*)(hb + (size_t)node * 128) + kg;

        float4v acc[4];
#pragma unroll
        for (int j = 0; j < 4; ++j) acc[j] = (float4v){0.f, 0.f, 0.f, 0.f};

#pragma unroll
        for (int kk = 0; kk < 8; ++kk) {
            short8 afrag = (kk < 4) ? xrow[kk * 4] : hrow[(kk - 4) * 4];
#pragma unroll
            for (int j = 0; j < 4; ++j)
                acc[j] = __builtin_amdgcn_mfma_f32_16x16x32_bf16(afrag, bfrag[j][kk], acc[j], 0, 0, 0);
        }
        // Epilogue: D col = lane&15, row = (lane>>4)*4 + r  [verified mapping]
#pragma unroll
        for (int j = 0; j < 4; ++j) {
            int col = (half * 4 + j) * 16 + (lane & 15);
#pragma unroll
            for (int r = 0; r < 4; ++r) {
                float v = acc[j][r] + bval[j];
                v = 1.f / (1.f + __expf(-v));
                out[(size_t)(s * 16 + kg * 4 + r) * 128 + col] = v;
            }
        }
    }
}

extern "C" void kernel_launch(void* const* d_in, const int* in_sizes, int n_in,
                              void* d_out, int out_size, void* d_ws, size_t ws_size,
                              hipStream_t stream) {
    const float* x    = (const float*)d_in[0];   // [N,128]
    const int*   adj  = (const int*)d_in[1];     // [E,2] (dst,src) int32
    const float* w    = (const float*)d_in[3];   // [256,128]
    const float* bias = (const float*)d_in[4];   // [128]
    float* out = (float*)d_out;

    // Workspace layout (round-0 proven):
    //   xb:  N*128 bf16 = 25,600,000 B @ 0
    //   hb:  N*128 bf16 = 25,600,000 B @ 25,600,000
    //   wp:  32768 bf16 =     65,536 B @ 51,200,000
    //   xf8: N*128 fp8  = 12,800,000 B @ 51,265,536   (total 64,065,536)
    unsigned short* xb = (unsigned short*)d_ws;
    unsigned short* hb = (unsigned short*)((char*)d_ws + 25600000);
    unsigned short* wp = (unsigned short*)((char*)d_ws + 51200000);
    unsigned* xf8 = (unsigned*)((char*)d_ws + 51265536);

    const bool use_f8 = ws_size >= 64065536;   // ws_size constant across calls

    prep_xw<<<12628, 256, 0, stream>>>((const float4*)x, (uint2*)xb, xf8, w, wp);
    if (use_f8)
        gather_w<<<3125, 256, 0, stream>>>((const uint4*)xf8, adj, (uint4*)hb);
    else
        gather_k<<<25000, 256, 0, stream>>>((const unsigned*)xb, adj, (unsigned*)hb);
    gemm_k<<<GEMM_BLOCKS, 256, 0, stream>>>(xb, hb, wp, bias, out);
}